// Round 14
// baseline (913.043 us; speedup 1.0000x reference)
//
#include <hip/hip_runtime.h>

#define E_CNT 32768
#define V_CNT 98304
#define D_ 128
#define VOCAB_ 2000
#define ITERS_ 6

typedef unsigned short u16;
typedef _Float16 f16;
typedef __attribute__((ext_vector_type(8))) _Float16 f16x8;
typedef __attribute__((ext_vector_type(4))) float f32x4;

__device__ __forceinline__ f32x4 MFh(f16x8 a, f16x8 b, f32x4 c) {
    return __builtin_amdgcn_mfma_f32_16x16x32_f16(a, b, c, 0, 0, 0);
}
__device__ __forceinline__ float sigmoid_f(float x) {
    return __builtin_amdgcn_rcpf(1.0f + __expf(-x));
}
__device__ __forceinline__ float tanh_f(float x) {
    float ax = fabsf(x);
    float t = fmaf(-2.0f, __builtin_amdgcn_rcpf(__expf(2.0f * ax) + 1.0f), 1.0f);
    return copysignf(t, x);
}

__global__ void detect_mask_kernel(const unsigned int* __restrict__ m, int* __restrict__ flag) {
    int i = blockIdx.x * 256 + threadIdx.x;
    if (i < 4096 && m[i] > 1u) atomicOr(flag, 1);
}

// Pack weights into MFMA fragment order.
// WvF (fp16): [nt(32)][kk(16)][lane(64)][8]  j = nt*16+(l&15), k = kk*32+(l>>4)*8+r
// WeF (fp16): [p(3)][nt(32)][kk(8)][64][8]
// OwF (fp16 hi/lo): [nt(125)][kk(4)][64][8]
__global__ void prep_kernel(
    const float* __restrict__ Wih_v2e, const float* __restrict__ Whh_v2e,
    const float* __restrict__ bih_v2e, const float* __restrict__ bhh_v2e,
    const float* __restrict__ Wih_e2v, const float* __restrict__ Whh_e2v,
    const float* __restrict__ bih_e2v, const float* __restrict__ bhh_e2v,
    const float* __restrict__ out_w,
    f16* __restrict__ WvF, f16* __restrict__ WeF,
    f16* __restrict__ OwFh, f16* __restrict__ OwFl,
    float* __restrict__ bv, float* __restrict__ be)
{
    int idx = blockIdx.x * 256 + threadIdx.x;
    if (idx < 262144) {
        const int r = idx & 7, l = (idx >> 3) & 63, t = idx >> 9;
        const int kk = t & 15, nt = t >> 4;
        const int j = nt * 16 + (l & 15);
        const int k = kk * 32 + (l >> 4) * 8 + r;
        const float w = (k < 384) ? Wih_v2e[j * 384 + k] : Whh_v2e[j * 128 + (k - 384)];
        WvF[idx] = (f16)w;
        return;
    }
    idx -= 262144;
    if (idx < 393216) {
        const int r = idx & 7, l = (idx >> 3) & 63, t = idx >> 9;  // t < 768
        const int kk = t & 7, nt = (t >> 3) & 31, p = t >> 8;
        const int j = nt * 16 + (l & 15);
        const int k = kk * 32 + (l >> 4) * 8 + r;
        const float w = (k < 128) ? Wih_e2v[(p * 512 + j) * 128 + k]
                                  : Whh_e2v[(p * 512 + j) * 128 + (k - 128)];
        WeF[idx] = (f16)w;
        return;
    }
    idx -= 393216;
    if (idx < 256000) {
        const int r = idx & 7, l = (idx >> 3) & 63, t = idx >> 9;  // t < 500
        const int kk = t & 3, nt = t >> 2;
        const int j = nt * 16 + (l & 15);
        const int k = kk * 32 + (l >> 4) * 8 + r;
        const float w = out_w[j * 128 + k];
        const f16 h = (f16)w;
        OwFh[idx] = h;
        OwFl[idx] = (f16)(w - (float)h);
        return;
    }
    idx -= 256000;
    if (idx < 512) { bv[idx] = bih_v2e[idx] + bhh_v2e[idx]; return; }
    idx -= 512;
    if (idx < 1536) { be[idx] = bih_e2v[idx] + bhh_e2v[idx]; return; }
}

// Persistent iteration kernel: 512 thr / 8 waves / 64 edges / all 6 iterations.
// LDS state in MFMA fragment order, FULLY DOUBLE-BUFFERED (ping-pong per iteration):
//   read buffer  = 64 KB STATIC  __shared__  (visible to the register allocator ->
//                  2-block occupancy model -> honest 128-VGPR budget, r8 mechanism)
//   write buffer = 64 KB DYNAMIC extern __shared__ (invisible to the allocator ->
//                  does not shrink the VGPR budget; runtime LDS = 128 KB)
// Double-buffering removes all WAR barriers: cells write buf[it^1] while GEMMs read
// buf[it] -> only TWO barriers/iter (HE-ready, iter-end) vs six (r12 diagnosis:
// ~1 block/CU resident, 6 barrier-locked phases serialized the whole chain).
// Unmasked lanes copy old h explicitly (write buffer must be fully populated).
__global__ __launch_bounds__(512)
void fused_kernel(
    const int* __restrict__ x_v,
    const float* __restrict__ emb,
    const float* __restrict__ eiw, const float* __restrict__ eib,
    const f16* __restrict__ WvF, const f16* __restrict__ WeF,
    const float* __restrict__ bv, const float* __restrict__ be,
    const void* __restrict__ mask, const int* __restrict__ flagp,
    float* __restrict__ cvG,
    f16* __restrict__ hvOut)
{
    __shared__ f16 HVs[24576];     // 48 KB static
    __shared__ f16 HEs[8192];      // 16 KB static
    extern __shared__ f16 dynbuf[];
    f16* HVd = dynbuf;             // 48 KB dynamic
    f16* HEd = dynbuf + 24576;     // 16 KB dynamic

    const int tid = threadIdx.x;
    const int c = tid >> 6, l = tid & 63;
    const int lr = l & 15, lk = l >> 4;
    const int e0 = blockIdx.x * 64;

    // ---- init h_v from embeddings into the it=0 read buffer (static)
    for (int i = tid; i < 64 * 48; i += 512) {
        const int row = i / 48, seg = i % 48;
        int id = x_v[(e0 + row) * 3 + (seg >> 4)];
        if (id < 0 || id > VOCAB_) id = VOCAB_;
        const float* s = emb + id * D_ + ((seg * 8) & 127);
        float4 a = *(const float4*)s, b = *(const float4*)(s + 4);
        f16x8 H;
        H[0] = (f16)a.x; H[1] = (f16)a.y; H[2] = (f16)a.z; H[3] = (f16)a.w;
        H[4] = (f16)b.x; H[5] = (f16)b.y; H[6] = (f16)b.z; H[7] = (f16)b.w;
        *(f16x8*)&HVs[((row >> 4) * 12 + (seg >> 2)) * 512 + (seg & 3) * 128 + (row & 15) * 8] = H;
    }
    for (int i = tid; i < 64 * 16; i += 512) {
        const int row = i / 16, seg = i % 16;
        f16x8 H;
        #pragma unroll
        for (int j = 0; j < 8; ++j) H[j] = (f16)(eiw[seg * 8 + j] + eib[seg * 8 + j]);
        *(f16x8*)&HEs[((row >> 4) * 4 + (seg >> 2)) * 512 + (seg & 3) * 128 + (row & 15) * 8] = H;
    }

    // ---- per-lane constants
    const int isByte = *flagp;
    unsigned mbits[3];
    #pragma unroll
    for (int p = 0; p < 3; ++p) {
        unsigned mb = 0;
        #pragma unroll
        for (int mt = 0; mt < 4; ++mt)
            #pragma unroll
            for (int r = 0; r < 4; ++r) {
                const int v = (e0 + mt * 16 + lk * 4 + r) * 3 + p;
                const bool m = isByte ? (((const unsigned char*)mask)[v] != 0)
                                      : (((const int*)mask)[v] != 0);
                mb |= (unsigned)m << (mt * 4 + r);
            }
        mbits[p] = mb;
    }
    const int d = c * 16 + lr;
    // fragment-coords of this thread's write column d (per-thread constants)
    const int wBase = (c >> 1) * 512 + ((c & 1) * 2 + (lr >> 3)) * 128 + lk * 32 + (lr & 7);
    float ce[4][4];
    #pragma unroll
    for (int mt = 0; mt < 4; ++mt)
        #pragma unroll
        for (int r = 0; r < 4; ++r) ce[mt][r] = 0.0f;

    __syncthreads();

    #pragma unroll 1
    for (int it = 0; it < ITERS_; ++it) {
        const f16* HVr = (it & 1) ? HVd : HVs;
        f16*       HVw = (it & 1) ? HVs : HVd;
        const f16* HEr = (it & 1) ? HEd : HEs;
        f16*       HEw = (it & 1) ? HEs : HEd;
        const f16* HVrl = HVr + l * 8;
        const f16* HErl = HEr + l * 8;
        const f16* HEwl = HEw + l * 8;

        // ======== vertex -> edge: GEMM reads HVr/HEr ========
        f32x4 acc[4][4];
        #pragma unroll
        for (int mt = 0; mt < 4; ++mt)
            #pragma unroll
            for (int g = 0; g < 4; ++g) acc[mt][g] = (f32x4)0.0f;

        #pragma unroll 2
        for (int kk = 0; kk < 16; ++kk) {
            f16x8 Ah[4];
            if (kk < 12) {
                #pragma unroll
                for (int mt = 0; mt < 4; ++mt)
                    Ah[mt] = *(const f16x8*)(HVrl + (mt * 12 + kk) * 512);
            } else {
                #pragma unroll
                for (int mt = 0; mt < 4; ++mt)
                    Ah[mt] = *(const f16x8*)(HErl + (mt * 4 + (kk - 12)) * 512);
            }
            #pragma unroll
            for (int g = 0; g < 4; ++g) {
                f16x8 B = *(const f16x8*)(WvF + (((g * 8 + c) * 16 + kk) * 64 + l) * 8);
                #pragma unroll
                for (int mt = 0; mt < 4; ++mt)
                    acc[mt][g] = MFh(Ah[mt], B, acc[mt][g]);
            }
        }
        // cellE writes HEw - nobody reads HEw until the barrier (no WAR barrier needed)
        {
            const float bvi = bv[d], bvf = bv[128 + d], bvg = bv[256 + d], bvo = bv[384 + d];
            #pragma unroll
            for (int mt = 0; mt < 4; ++mt)
                #pragma unroll
                for (int r = 0; r < 4; ++r) {
                    float gi = sigmoid_f(acc[mt][0][r] + bvi);
                    float gf = sigmoid_f(acc[mt][1][r] + bvf);
                    float gg = tanh_f(acc[mt][2][r] + bvg);
                    float go = sigmoid_f(acc[mt][3][r] + bvo);
                    float cn = gf * ce[mt][r] + gi * gg;
                    ce[mt][r] = cn;
                    HEw[wBase + mt * 2048 + r * 8] = (f16)(go * tanh_f(cn));
                }
        }
        __syncthreads();   // barrier 1: HEw visible for e2v

        // ======== edge -> vertex: 3 p-GEMMs + cells, NO internal barriers ========
        // GEMMs read HEw (new h_e) + HVr (old h_v); cells write HVw. Disjoint buffers.
        #pragma unroll 1
        for (int p = 0; p < 3; ++p) {
            #pragma unroll
            for (int mt = 0; mt < 4; ++mt)
                #pragma unroll
                for (int g = 0; g < 4; ++g) acc[mt][g] = (f32x4)0.0f;

            #pragma unroll 2
            for (int kk = 0; kk < 8; ++kk) {
                f16x8 Ah[4];
                if (kk < 4) {
                    #pragma unroll
                    for (int mt = 0; mt < 4; ++mt)
                        Ah[mt] = *(const f16x8*)(HEwl + (mt * 4 + kk) * 512);
                } else {
                    #pragma unroll
                    for (int mt = 0; mt < 4; ++mt)
                        Ah[mt] = *(const f16x8*)(HVrl + (mt * 12 + p * 4 + (kk - 4)) * 512);
                }
                #pragma unroll
                for (int g = 0; g < 4; ++g) {
                    f16x8 B = *(const f16x8*)(WeF + ((((p * 32) + (g * 8 + c)) * 8 + kk) * 64 + l) * 8);
                    #pragma unroll
                    for (int mt = 0; mt < 4; ++mt)
                        acc[mt][g] = MFh(Ah[mt], B, acc[mt][g]);
                }
            }
            const float bei = be[p * 512 + d], bef = be[p * 512 + 128 + d];
            const float beg = be[p * 512 + 256 + d], beo = be[p * 512 + 384 + d];
            #pragma unroll
            for (int mt = 0; mt < 4; ++mt)
                #pragma unroll
                for (int r = 0; r < 4; ++r) {
                    const int off = wBase + mt * 6144 + p * 2048 + r * 8;
                    const f16 hold = HVr[off];              // old h (kept when unmasked)
                    const bool m = (mbits[p] >> (mt * 4 + r)) & 1u;
                    const int row = mt * 16 + lk * 4 + r;
                    const size_t co = ((size_t)(e0 + row) * 3 + p) * 128 + d;
                    float cvold = (it == 0) ? 0.0f : cvG[co];
                    float gi = sigmoid_f(acc[mt][0][r] + bei);
                    float gf = sigmoid_f(acc[mt][1][r] + bef);
                    float gg = tanh_f(acc[mt][2][r] + beg);
                    float go = sigmoid_f(acc[mt][3][r] + beo);
                    float cn = gf * cvold + gi * gg;
                    if (m) cvG[co] = cn;
                    f16 val = m ? (f16)(go * tanh_f(cn)) : hold;
                    HVw[off] = val;
                }
        }
        __syncthreads();   // barrier 2: iter end - HVw/HEw settled, old reads done
    }

    // ---- write final h_v: last write buffer = HVw(it=5) = HVs (5 odd)
    const f16* HVf = ((ITERS_ - 1) & 1) ? HVs : HVd;
    for (int i = tid; i < 64 * 48; i += 512) {
        const int row = i / 48, seg = i % 48;
        *(f16x8*)&hvOut[(size_t)(e0 + row) * 384 + seg * 8] =
            *(const f16x8*)&HVf[((row >> 4) * 12 + (seg >> 2)) * 512 + (seg & 3) * 128 + (row & 15) * 8];
    }
}

// logits = h_v @ out_w^T + out_b, swapped MFMA operands (A=out_w, B=h_v) -> each lane
// holds 4 consecutive vocab cols for one vertex -> float4 stores.
// 768 blocks x 256 thr (4 waves x 32 verts = 128 verts/block; 768*128 = 98304 = FULL
// coverage - r12/r13 bug: grid was 384, half the logits never written, absmax 0.082).
// 48 KB LDS anchor -> compiler occupancy model: 3 blocks/CU -> VGPR budget ~170 >= ~130.
// Register double-buffer of W fragments (8 f16x8 in flight for nt+1).
__global__ __launch_bounds__(256) void proj_kernel(
    const f16* __restrict__ hv,
    const f16* __restrict__ WFh, const f16* __restrict__ WFl,
    const float* __restrict__ out_b, float* __restrict__ out)
{
    __shared__ char occ_pad[49152];
    const int tid = threadIdx.x, l = tid & 63;
    occ_pad[tid] = (char)tid;
    __syncthreads();
    {
        int keep = (int)occ_pad[(tid + 1) & 255];
        asm volatile("" :: "v"(keep));   // keep the pad live (occupancy anchor)
    }

    const int wid = blockIdx.x * 4 + (tid >> 6);   // 0..3071
    const int v0 = wid * 32;
    const int lr = l & 15, lk = l >> 4;

    f16x8 Bv[2][4];
    #pragma unroll
    for (int vt = 0; vt < 2; ++vt)
        #pragma unroll
        for (int kk = 0; kk < 4; ++kk)
            Bv[vt][kk] = *(const f16x8*)(hv + (v0 + vt * 16 + lr) * D_ + kk * 32 + lk * 8);

    f16x8 Wc[8];
    #pragma unroll
    for (int kk = 0; kk < 4; ++kk) {
        Wc[kk]     = *(const f16x8*)(WFh + ((kk) * 64 + l) * 8);
        Wc[4 + kk] = *(const f16x8*)(WFl + ((kk) * 64 + l) * 8);
    }

    #pragma unroll 2
    for (int nt = 0; nt < 125; ++nt) {
        f16x8 Wn[8];
        if (nt < 124) {
            #pragma unroll
            for (int kk = 0; kk < 4; ++kk) {
                const int fb = (((nt + 1) * 4 + kk) * 64 + l) * 8;
                Wn[kk]     = *(const f16x8*)(WFh + fb);
                Wn[4 + kk] = *(const f16x8*)(WFl + fb);
            }
        }
        f32x4 t0 = (f32x4)0.0f, t1 = (f32x4)0.0f, u0 = (f32x4)0.0f, u1 = (f32x4)0.0f;
        #pragma unroll
        for (int kk = 0; kk < 4; ++kk) {
            t0 = MFh(Wc[kk], Bv[0][kk], t0);
            t1 = MFh(Wc[kk], Bv[1][kk], t1);
            u0 = MFh(Wc[4 + kk], Bv[0][kk], u0);
            u1 = MFh(Wc[4 + kk], Bv[1][kk], u1);
        }
        f32x4 a0 = t0 + u0;
        f32x4 a1 = t1 + u1;
        const int n0 = nt * 16 + lk * 4;
        const float4 bb = *(const float4*)&out_b[n0];
        {
            const size_t v = (size_t)(v0 + lr);
            float4 o = make_float4(a0[0] + bb.x, a0[1] + bb.y, a0[2] + bb.z, a0[3] + bb.w);
            *(float4*)&out[v * VOCAB_ + n0] = o;
        }
        {
            const size_t v = (size_t)(v0 + 16 + lr);
            float4 o = make_float4(a1[0] + bb.x, a1[1] + bb.y, a1[2] + bb.z, a1[3] + bb.w);
            *(float4*)&out[v * VOCAB_ + n0] = o;
        }
        #pragma unroll
        for (int q = 0; q < 8; ++q) Wc[q] = Wn[q];
    }
}

extern "C" void kernel_launch(void* const* d_in, const int* in_sizes, int n_in,
                              void* d_out, int out_size, void* d_ws, size_t ws_size,
                              hipStream_t stream)
{
    const int*   x_v     = (const int*)  d_in[0];
    const void*  mask    = d_in[1];
    const float* emb     = (const float*)d_in[2];
    const float* eiw     = (const float*)d_in[3];
    const float* eib     = (const float*)d_in[4];
    const float* Wih_v2e = (const float*)d_in[5];
    const float* Whh_v2e = (const float*)d_in[6];
    const float* bih_v2e = (const float*)d_in[7];
    const float* bhh_v2e = (const float*)d_in[8];
    const float* Wih_e2v = (const float*)d_in[9];
    const float* Whh_e2v = (const float*)d_in[10];
    const float* bih_e2v = (const float*)d_in[11];
    const float* bhh_e2v = (const float*)d_in[12];
    const float* out_w   = (const float*)d_in[13];
    const float* out_b   = (const float*)d_in[14];
    float* out = (float*)d_out;

    // d_ws carve (~78 MB)
    char* ws = (char*)d_ws;
    f16*   hv   = (f16*)(ws);                  // 25165824 B
    f16*   WvF  = (f16*)(ws + 25165824);       // 524288
    f16*   WeF  = (f16*)(ws + 25690112);       // 786432
    f16*   OwFh = (f16*)(ws + 26476544);       // 512000
    f16*   OwFl = (f16*)(ws + 26988544);       // 512000
    float* bv   = (float*)(ws + 27500544);     // 2048
    float* be   = (float*)(ws + 27502592);     // 6144
    int*   flag = (int*)(ws + 27508736);       // 4
    float* cvG  = (float*)(ws + 27525120);     // 50331648  [E][3][128]

    hipFuncSetAttribute(reinterpret_cast<const void*>(fused_kernel),
                        hipFuncAttributeMaxDynamicSharedMemorySize, 65536);

    hipMemsetAsync(flag, 0, 4, stream);
    detect_mask_kernel<<<16, 256, 0, stream>>>((const unsigned int*)mask, flag);
    prep_kernel<<<3568, 256, 0, stream>>>(Wih_v2e, Whh_v2e, bih_v2e, bhh_v2e,
                                          Wih_e2v, Whh_e2v, bih_e2v, bhh_e2v, out_w,
                                          WvF, WeF, OwFh, OwFl, bv, be);
    fused_kernel<<<E_CNT / 64, 512, 65536, stream>>>(x_v, emb, eiw, eib,
                                                     WvF, WeF, bv, be,
                                                     mask, flag, cvG, hv);
    proj_kernel<<<V_CNT / 128, 256, 0, stream>>>(hv, OwFh, OwFl, out_b, out);
}

// Round 15
// 794.044 us; speedup vs baseline: 1.1499x; 1.1499x over previous
//
#include <hip/hip_runtime.h>

#define E_CNT 32768
#define V_CNT 98304
#define D_ 128
#define VOCAB_ 2000
#define ITERS_ 6

typedef unsigned short u16;
typedef _Float16 f16;
typedef __attribute__((ext_vector_type(8))) _Float16 f16x8;
typedef __attribute__((ext_vector_type(4))) float f32x4;

__device__ __forceinline__ f32x4 MFh(f16x8 a, f16x8 b, f32x4 c) {
    return __builtin_amdgcn_mfma_f32_16x16x32_f16(a, b, c, 0, 0, 0);
}
__device__ __forceinline__ float sigmoid_f(float x) {
    return __builtin_amdgcn_rcpf(1.0f + __expf(-x));
}
__device__ __forceinline__ float tanh_f(float x) {
    float ax = fabsf(x);
    float t = fmaf(-2.0f, __builtin_amdgcn_rcpf(__expf(2.0f * ax) + 1.0f), 1.0f);
    return copysignf(t, x);
}

__global__ void detect_mask_kernel(const unsigned int* __restrict__ m, int* __restrict__ flag) {
    int i = blockIdx.x * 256 + threadIdx.x;
    if (i < 4096 && m[i] > 1u) atomicOr(flag, 1);
}

// Pack weights into MFMA fragment order.
// WvF (fp16): [nt(32)][kk(16)][lane(64)][8]  j = nt*16+(l&15), k = kk*32+(l>>4)*8+r
// WeF (fp16): [p(3)][nt(32)][kk(8)][64][8]
// OwF (fp16, SINGLE precision term - err ~5e-5 << 1.64e-3): [nt(125)][kk(4)][64][8]
__global__ void prep_kernel(
    const float* __restrict__ Wih_v2e, const float* __restrict__ Whh_v2e,
    const float* __restrict__ bih_v2e, const float* __restrict__ bhh_v2e,
    const float* __restrict__ Wih_e2v, const float* __restrict__ Whh_e2v,
    const float* __restrict__ bih_e2v, const float* __restrict__ bhh_e2v,
    const float* __restrict__ out_w,
    f16* __restrict__ WvF, f16* __restrict__ WeF, f16* __restrict__ OwF,
    float* __restrict__ bv, float* __restrict__ be)
{
    int idx = blockIdx.x * 256 + threadIdx.x;
    if (idx < 262144) {
        const int r = idx & 7, l = (idx >> 3) & 63, t = idx >> 9;
        const int kk = t & 15, nt = t >> 4;
        const int j = nt * 16 + (l & 15);
        const int k = kk * 32 + (l >> 4) * 8 + r;
        const float w = (k < 384) ? Wih_v2e[j * 384 + k] : Whh_v2e[j * 128 + (k - 384)];
        WvF[idx] = (f16)w;
        return;
    }
    idx -= 262144;
    if (idx < 393216) {
        const int r = idx & 7, l = (idx >> 3) & 63, t = idx >> 9;  // t < 768
        const int kk = t & 7, nt = (t >> 3) & 31, p = t >> 8;
        const int j = nt * 16 + (l & 15);
        const int k = kk * 32 + (l >> 4) * 8 + r;
        const float w = (k < 128) ? Wih_e2v[(p * 512 + j) * 128 + k]
                                  : Whh_e2v[(p * 512 + j) * 128 + (k - 128)];
        WeF[idx] = (f16)w;
        return;
    }
    idx -= 393216;
    if (idx < 256000) {
        const int r = idx & 7, l = (idx >> 3) & 63, t = idx >> 9;  // t < 500
        const int kk = t & 3, nt = t >> 2;
        const int j = nt * 16 + (l & 15);
        const int k = kk * 32 + (l >> 4) * 8 + r;
        OwF[idx] = (f16)out_w[j * 128 + k];
        return;
    }
    idx -= 256000;
    if (idx < 512) { bv[idx] = bih_v2e[idx] + bhh_v2e[idx]; return; }
    idx -= 512;
    if (idx < 1536) { be[idx] = bih_e2v[idx] + bhh_e2v[idx]; return; }
}

// Persistent iteration kernel: 512 thr / 8 waves / 64 edges / all 6 iterations.
// Single-buffer fragment-order LDS (64 KB static -> 2 blocks/CU co-resident; r14
// showed co-residency beats barrier reduction), 6 barriers/iter.
// r15 FIX: c_v in COALESCED fragment layout - cvG4[(blk*3+p)*4+mt][tid] as float4.
// Old layout ([e][p][128] scalar, lane stride 1536B) made every cvG access 64
// transactions: ~50K transactions/block-iter = the dominant stall (r14 arithmetic:
// 123K cyc/iter observed vs ~5K compute). Now ONE coalesced float4 load+store per
// (wave,p,mt): 256x fewer transactions.
__global__ __launch_bounds__(512)
void fused_kernel(
    const int* __restrict__ x_v,
    const float* __restrict__ emb,
    const float* __restrict__ eiw, const float* __restrict__ eib,
    const f16* __restrict__ WvF, const f16* __restrict__ WeF,
    const float* __restrict__ bv, const float* __restrict__ be,
    const void* __restrict__ mask, const int* __restrict__ flagp,
    float4* __restrict__ cvG4,
    f16* __restrict__ hvOut)
{
    __shared__ f16 HV[24576];   // 48 KB, fragment order
    __shared__ f16 HE[8192];    // 16 KB, fragment order

    const int tid = threadIdx.x;
    const int c = tid >> 6, l = tid & 63;
    const int lr = l & 15, lk = l >> 4;
    const int e0 = blockIdx.x * 64;

    // ---- init h_v from embeddings (fp16x8 chunks into fragment slots)
    for (int i = tid; i < 64 * 48; i += 512) {
        const int row = i / 48, seg = i % 48;
        int id = x_v[(e0 + row) * 3 + (seg >> 4)];
        if (id < 0 || id > VOCAB_) id = VOCAB_;
        const float* s = emb + id * D_ + ((seg * 8) & 127);
        float4 a = *(const float4*)s, b = *(const float4*)(s + 4);
        f16x8 H;
        H[0] = (f16)a.x; H[1] = (f16)a.y; H[2] = (f16)a.z; H[3] = (f16)a.w;
        H[4] = (f16)b.x; H[5] = (f16)b.y; H[6] = (f16)b.z; H[7] = (f16)b.w;
        *(f16x8*)&HV[((row >> 4) * 12 + (seg >> 2)) * 512 + (seg & 3) * 128 + (row & 15) * 8] = H;
    }
    // ---- init h_e (same vector for every edge)
    for (int i = tid; i < 64 * 16; i += 512) {
        const int row = i / 16, seg = i % 16;
        f16x8 H;
        #pragma unroll
        for (int j = 0; j < 8; ++j) H[j] = (f16)(eiw[seg * 8 + j] + eib[seg * 8 + j]);
        *(f16x8*)&HE[((row >> 4) * 4 + (seg >> 2)) * 512 + (seg & 3) * 128 + (row & 15) * 8] = H;
    }

    // ---- per-lane constants
    const int isByte = *flagp;
    unsigned mbits[3];
    #pragma unroll
    for (int p = 0; p < 3; ++p) {
        unsigned mb = 0;
        #pragma unroll
        for (int mt = 0; mt < 4; ++mt)
            #pragma unroll
            for (int r = 0; r < 4; ++r) {
                const int v = (e0 + mt * 16 + lk * 4 + r) * 3 + p;
                const bool m = isByte ? (((const unsigned char*)mask)[v] != 0)
                                      : (((const int*)mask)[v] != 0);
                mb |= (unsigned)m << (mt * 4 + r);
            }
        mbits[p] = mb;
    }
    const int d = c * 16 + lr;
    // fragment-coords of this thread's write column d (per-thread constants)
    const int wBase = (c >> 1) * 512 + ((c & 1) * 2 + (lr >> 3)) * 128 + lk * 32 + (lr & 7);
    float ce[4][4];
    #pragma unroll
    for (int mt = 0; mt < 4; ++mt)
        #pragma unroll
        for (int r = 0; r < 4; ++r) ce[mt][r] = 0.0f;

    __syncthreads();

    const f16* HVl = HV + l * 8;   // lane-linear bases: all reads are base + imm
    const f16* HEl = HE + l * 8;
    const size_t cvBase = (size_t)blockIdx.x * 12 * 512 + tid;   // float4 units

    #pragma unroll 1
    for (int it = 0; it < ITERS_; ++it) {
        // ======== vertex -> edge ========
        {
            f32x4 acc[4][4];
            #pragma unroll
            for (int mt = 0; mt < 4; ++mt)
                #pragma unroll
                for (int g = 0; g < 4; ++g) acc[mt][g] = (f32x4)0.0f;

            #pragma unroll 2
            for (int kk = 0; kk < 16; ++kk) {
                f16x8 Ah[4];
                if (kk < 12) {
                    #pragma unroll
                    for (int mt = 0; mt < 4; ++mt)
                        Ah[mt] = *(const f16x8*)(HVl + (mt * 12 + kk) * 512);
                } else {
                    #pragma unroll
                    for (int mt = 0; mt < 4; ++mt)
                        Ah[mt] = *(const f16x8*)(HEl + (mt * 4 + (kk - 12)) * 512);
                }
                #pragma unroll
                for (int g = 0; g < 4; ++g) {
                    f16x8 B = *(const f16x8*)(WvF + (((g * 8 + c) * 16 + kk) * 64 + l) * 8);
                    #pragma unroll
                    for (int mt = 0; mt < 4; ++mt)
                        acc[mt][g] = MFh(Ah[mt], B, acc[mt][g]);
                }
            }
            __syncthreads();   // all HE reads done before HE writes
            const float bvi = bv[d], bvf = bv[128 + d], bvg = bv[256 + d], bvo = bv[384 + d];
            #pragma unroll
            for (int mt = 0; mt < 4; ++mt)
                #pragma unroll
                for (int r = 0; r < 4; ++r) {
                    float gi = sigmoid_f(acc[mt][0][r] + bvi);
                    float gf = sigmoid_f(acc[mt][1][r] + bvf);
                    float gg = tanh_f(acc[mt][2][r] + bvg);
                    float go = sigmoid_f(acc[mt][3][r] + bvo);
                    float cn = gf * ce[mt][r] + gi * gg;
                    ce[mt][r] = cn;
                    HE[wBase + mt * 2048 + r * 8] = (f16)(go * tanh_f(cn));
                }
            __syncthreads();   // HE complete before e2v reads
        }
        // ======== edge -> vertex (3 position-specific LSTMs) ========
        #pragma unroll 1
        for (int p = 0; p < 3; ++p) {
            f32x4 acc[4][4];
            #pragma unroll
            for (int mt = 0; mt < 4; ++mt)
                #pragma unroll
                for (int g = 0; g < 4; ++g) acc[mt][g] = (f32x4)0.0f;

            #pragma unroll 2
            for (int kk = 0; kk < 8; ++kk) {
                f16x8 Ah[4];
                if (kk < 4) {
                    #pragma unroll
                    for (int mt = 0; mt < 4; ++mt)
                        Ah[mt] = *(const f16x8*)(HEl + (mt * 4 + kk) * 512);
                } else {
                    #pragma unroll
                    for (int mt = 0; mt < 4; ++mt)
                        Ah[mt] = *(const f16x8*)(HVl + (mt * 12 + p * 4 + (kk - 4)) * 512);
                }
                #pragma unroll
                for (int g = 0; g < 4; ++g) {
                    f16x8 B = *(const f16x8*)(WeF + ((((p * 32) + (g * 8 + c)) * 8 + kk) * 64 + l) * 8);
                    #pragma unroll
                    for (int mt = 0; mt < 4; ++mt)
                        acc[mt][g] = MFh(Ah[mt], B, acc[mt][g]);
                }
            }
            __syncthreads();   // all HV[p]/HE reads done before HV[p] writes
            const float bei = be[p * 512 + d], bef = be[p * 512 + 128 + d];
            const float beg = be[p * 512 + 256 + d], beo = be[p * 512 + 384 + d];
            #pragma unroll
            for (int mt = 0; mt < 4; ++mt) {
                // ONE coalesced float4 load + store per (wave,p,mt)
                const size_t ci = cvBase + (p * 4 + mt) * 512;
                float cvv[4] = {0.0f, 0.0f, 0.0f, 0.0f};
                if (it > 0) {
                    float4 t = cvG4[ci];
                    cvv[0] = t.x; cvv[1] = t.y; cvv[2] = t.z; cvv[3] = t.w;
                }
                #pragma unroll
                for (int r = 0; r < 4; ++r) {
                    if ((mbits[p] >> (mt * 4 + r)) & 1u) {
                        float gi = sigmoid_f(acc[mt][0][r] + bei);
                        float gf = sigmoid_f(acc[mt][1][r] + bef);
                        float gg = tanh_f(acc[mt][2][r] + beg);
                        float go = sigmoid_f(acc[mt][3][r] + beo);
                        float cn = gf * cvv[r] + gi * gg;
                        cvv[r] = cn;
                        HV[wBase + mt * 6144 + p * 2048 + r * 8] = (f16)(go * tanh_f(cn));
                    }
                }
                cvG4[ci] = make_float4(cvv[0], cvv[1], cvv[2], cvv[3]);
            }
            // no barrier between cell(p) and GEMM(p+1): cell writes HV tiles 4p..4p+3,
            // GEMM(p+1) reads tiles 4(p+1).. and HE - disjoint
        }
        __syncthreads();       // HV writes complete before next v2e (or copy-out)
    }

    // ---- write final h_v (fp16) for the projection kernel: [vertex][128] row-major
    for (int i = tid; i < 64 * 48; i += 512) {
        const int row = i / 48, seg = i % 48;
        *(f16x8*)&hvOut[(size_t)(e0 + row) * 384 + seg * 8] =
            *(const f16x8*)&HV[((row >> 4) * 12 + (seg >> 2)) * 512 + (seg & 3) * 128 + (row & 15) * 8];
    }
}

// logits = h_v @ out_w^T + out_b, swapped MFMA operands (A=out_w, B=h_v) -> each lane
// holds 4 consecutive vocab cols for one vertex -> float4 stores.
// SINGLE fp16 W term (r15: halves W traffic and MFMA count; err ~5e-5).
// 768 blocks x 256 thr (4 waves x 32 verts = 128 verts/block -> full 98304 coverage).
// 48 KB LDS anchor -> 3 blocks/CU model -> VGPR budget ~170 >= ~90. W register dbuf.
__global__ __launch_bounds__(256) void proj_kernel(
    const f16* __restrict__ hv, const f16* __restrict__ WF,
    const float* __restrict__ out_b, float* __restrict__ out)
{
    __shared__ char occ_pad[49152];
    const int tid = threadIdx.x, l = tid & 63;
    occ_pad[tid] = (char)tid;
    __syncthreads();
    {
        int keep = (int)occ_pad[(tid + 1) & 255];
        asm volatile("" :: "v"(keep));   // keep the pad live (occupancy anchor)
    }

    const int wid = blockIdx.x * 4 + (tid >> 6);   // 0..3071
    const int v0 = wid * 32;
    const int lr = l & 15, lk = l >> 4;

    f16x8 Bv[2][4];
    #pragma unroll
    for (int vt = 0; vt < 2; ++vt)
        #pragma unroll
        for (int kk = 0; kk < 4; ++kk)
            Bv[vt][kk] = *(const f16x8*)(hv + (v0 + vt * 16 + lr) * D_ + kk * 32 + lk * 8);

    f16x8 Wc[4];
    #pragma unroll
    for (int kk = 0; kk < 4; ++kk)
        Wc[kk] = *(const f16x8*)(WF + (kk * 64 + l) * 8);

    #pragma unroll 2
    for (int nt = 0; nt < 125; ++nt) {
        f16x8 Wn[4];
        if (nt < 124) {
            #pragma unroll
            for (int kk = 0; kk < 4; ++kk)
                Wn[kk] = *(const f16x8*)(WF + (((nt + 1) * 4 + kk) * 64 + l) * 8);
        }
        f32x4 a0 = (f32x4)0.0f, a1 = (f32x4)0.0f;
        #pragma unroll
        for (int kk = 0; kk < 4; ++kk) {
            a0 = MFh(Wc[kk], Bv[0][kk], a0);
            a1 = MFh(Wc[kk], Bv[1][kk], a1);
        }
        const int n0 = nt * 16 + lk * 4;
        const float4 bb = *(const float4*)&out_b[n0];
        {
            const size_t v = (size_t)(v0 + lr);
            float4 o = make_float4(a0[0] + bb.x, a0[1] + bb.y, a0[2] + bb.z, a0[3] + bb.w);
            *(float4*)&out[v * VOCAB_ + n0] = o;
        }
        {
            const size_t v = (size_t)(v0 + 16 + lr);
            float4 o = make_float4(a1[0] + bb.x, a1[1] + bb.y, a1[2] + bb.z, a1[3] + bb.w);
            *(float4*)&out[v * VOCAB_ + n0] = o;
        }
        #pragma unroll
        for (int q = 0; q < 4; ++q) Wc[q] = Wn[q];
    }
}

extern "C" void kernel_launch(void* const* d_in, const int* in_sizes, int n_in,
                              void* d_out, int out_size, void* d_ws, size_t ws_size,
                              hipStream_t stream)
{
    const int*   x_v     = (const int*)  d_in[0];
    const void*  mask    = d_in[1];
    const float* emb     = (const float*)d_in[2];
    const float* eiw     = (const float*)d_in[3];
    const float* eib     = (const float*)d_in[4];
    const float* Wih_v2e = (const float*)d_in[5];
    const float* Whh_v2e = (const float*)d_in[6];
    const float* bih_v2e = (const float*)d_in[7];
    const float* bhh_v2e = (const float*)d_in[8];
    const float* Wih_e2v = (const float*)d_in[9];
    const float* Whh_e2v = (const float*)d_in[10];
    const float* bih_e2v = (const float*)d_in[11];
    const float* bhh_e2v = (const float*)d_in[12];
    const float* out_w   = (const float*)d_in[13];
    const float* out_b   = (const float*)d_in[14];
    float* out = (float*)d_out;

    // d_ws carve (~77.3 MB)
    char* ws = (char*)d_ws;
    f16*    hv   = (f16*)(ws);                  // 25165824 B
    f16*    WvF  = (f16*)(ws + 25165824);       // 524288
    f16*    WeF  = (f16*)(ws + 25690112);       // 786432
    f16*    OwF  = (f16*)(ws + 26476544);       // 512000
    float*  bv   = (float*)(ws + 26988544);     // 2048
    float*  be   = (float*)(ws + 26990592);     // 6144
    int*    flag = (int*)(ws + 26996736);       // 4
    float4* cvG4 = (float4*)(ws + 27000832);    // 50331648  [blk][p][mt][tid] float4

    hipMemsetAsync(flag, 0, 4, stream);
    detect_mask_kernel<<<16, 256, 0, stream>>>((const unsigned int*)mask, flag);
    prep_kernel<<<3568, 256, 0, stream>>>(Wih_v2e, Whh_v2e, bih_v2e, bhh_v2e,
                                          Wih_e2v, Whh_e2v, bih_e2v, bhh_e2v, out_w,
                                          WvF, WeF, OwF, bv, be);
    fused_kernel<<<E_CNT / 64, 512, 0, stream>>>(x_v, emb, eiw, eib,
                                                 WvF, WeF, bv, be,
                                                 mask, flag, cvG4, hv);
    proj_kernel<<<V_CNT / 128, 256, 0, stream>>>(hv, OwF, out_b, out);
}